// Round 11
// baseline (815.275 us; speedup 1.0000x reference)
//
#include <hip/hip_runtime.h>
#include <hip/hip_bf16.h>
#include <math.h>

// Problem constants (reference: N=8192, H=2048, E=8, K=2, CF=1.25)
#define NTOK 8192
#define HDIM 2048
#define NEXP 8
#define TOPK 2
#define CAP  1280            // ceil(1.25 * 8192 / 8)
#define FF   4096            // 2*H
#define BK   32              // GEMM K-step

typedef float  f32x4  __attribute__((ext_vector_type(4)));
typedef __bf16 bf16x8 __attribute__((ext_vector_type(8)));

typedef __attribute__((address_space(1))) const unsigned int gas_u32;
typedef __attribute__((address_space(3))) unsigned int las_u32;

__device__ __forceinline__ void gload16(const void* g, void* l) {
    // async global -> LDS, 16 B per lane; LDS dest = wave-uniform base + lane*16
    __builtin_amdgcn_global_load_lds((gas_u32*)g, (las_u32*)l, 16, 0, 0);
}

__device__ __forceinline__ ushort f2bf(float f) {
    union { float f; unsigned u; } c; c.f = f;
    unsigned u = c.u;
    unsigned r = (u + 0x7FFFu + ((u >> 16) & 1u)) >> 16;   // RNE
    return (ushort)r;
}
__device__ __forceinline__ float bf2f(ushort h) {
    union { unsigned u; float f; } c; c.u = ((unsigned)h) << 16;
    return c.f;
}

// ---------------- tokens f32 -> bf16 ----------------
__global__ void k_convert(const float* __restrict__ src, ushort* __restrict__ dst) {
    int i = (blockIdx.x * 256 + threadIdx.x) * 8;
    float4 a = *(const float4*)(src + i);
    float4 b = *(const float4*)(src + i + 4);
    uint4 o;
    o.x = (unsigned)f2bf(a.x) | ((unsigned)f2bf(a.y) << 16);
    o.y = (unsigned)f2bf(a.z) | ((unsigned)f2bf(a.w) << 16);
    o.z = (unsigned)f2bf(b.x) | ((unsigned)f2bf(b.y) << 16);
    o.w = (unsigned)f2bf(b.z) | ((unsigned)f2bf(b.w) << 16);
    *(uint4*)(dst + i) = o;
}

// ---------------- router: logits (f64 accum), top-2, softmax ----------------
__global__ void k_router(const float* __restrict__ tokens, const float* __restrict__ Wr,
                         const float* __restrict__ br, int* __restrict__ eids,
                         float* __restrict__ probs) {
    int wave = threadIdx.x >> 6, lane = threadIdx.x & 63;
    int t = blockIdx.x * 4 + wave;
    const float* tp = tokens + (size_t)t * HDIM;
    double acc[NEXP];
    #pragma unroll
    for (int e = 0; e < NEXP; ++e) acc[e] = 0.0;
    for (int j = 0; j < HDIM / 64; ++j) {
        float x = tp[j * 64 + lane];
        #pragma unroll
        for (int e = 0; e < NEXP; ++e)
            acc[e] += (double)x * (double)Wr[e * HDIM + j * 64 + lane];
    }
    #pragma unroll
    for (int e = 0; e < NEXP; ++e) {
        #pragma unroll
        for (int off = 32; off; off >>= 1) acc[e] += __shfl_xor(acc[e], off, 64);
    }
    if (lane == 0) {
        float lg[NEXP];
        #pragma unroll
        for (int e = 0; e < NEXP; ++e) lg[e] = (float)acc[e] + br[e];
        int e0 = 0; float s0 = lg[0];
        #pragma unroll
        for (int e = 1; e < NEXP; ++e) if (lg[e] > s0) { s0 = lg[e]; e0 = e; }
        int e1 = -1; float s1 = -1e30f;
        #pragma unroll
        for (int e = 0; e < NEXP; ++e) if (e != e0 && lg[e] > s1) { s1 = lg[e]; e1 = e; }
        float ex = expf(s1 - s0);
        float den = 1.f + ex;
        eids[t * 2] = e0; eids[t * 2 + 1] = e1;
        probs[t * 2] = 1.f / den; probs[t * 2 + 1] = ex / den;
    }
}

// ---------------- deterministic rank/capacity assignment (1 block, 1 wave) ----------------
__global__ void k_assign(const int* __restrict__ eids, int* __restrict__ tok_map,
                         int* __restrict__ dest) {
    __shared__ int cnt[64][NEXP];
    int l = threadIdx.x;
    for (int i = l; i < NEXP * CAP; i += 64) tok_map[i] = 0;
    int c[NEXP];
    #pragma unroll
    for (int e = 0; e < NEXP; ++e) c[e] = 0;
    const int base = l * 256;
    for (int i = 0; i < 256; ++i) {
        int ee = eids[base + i];
        #pragma unroll
        for (int e = 0; e < NEXP; ++e) c[e] += (ee == e);
    }
    #pragma unroll
    for (int e = 0; e < NEXP; ++e) cnt[l][e] = c[e];
    __syncthreads();
    if (l < NEXP) {
        int run = 0;
        for (int b = 0; b < 64; ++b) { int v = cnt[b][l]; cnt[b][l] = run; run += v; }
    }
    __syncthreads();
    int off[NEXP];
    #pragma unroll
    for (int e = 0; e < NEXP; ++e) off[e] = cnt[l][e];
    for (int i = 0; i < 256; ++i) {
        int d = base + i;
        int ee = eids[d];
        int r = -1;
        #pragma unroll
        for (int e = 0; e < NEXP; ++e) { bool m = (ee == e); if (m) r = off[e]; off[e] += m; }
        if (r < CAP) { tok_map[ee * CAP + r] = d >> 1; dest[d] = ee * CAP + r; }
        else dest[d] = -1;
    }
}

// ---------------- W [E][Kd][Nd] f32 -> WT [E][Nd][Kd] bf16, 64x64 tiles ----------------
__global__ __launch_bounds__(256) void k_transpose(const float* __restrict__ src,
                                                   ushort* __restrict__ dst,
                                                   int Kd, int Nd) {
    __shared__ float tl[64][65];
    int e = blockIdx.z;
    int k0 = blockIdx.x * 64, n0 = blockIdx.y * 64;
    const float* s = src + (size_t)e * Kd * Nd;
    ushort* d = dst + (size_t)e * Kd * Nd;
    int tid = threadIdx.x;
    #pragma unroll
    for (int i = 0; i < 4; ++i) {
        int flat = (i * 256 + tid) * 4;
        int kk = flat >> 6, nn = flat & 63;
        float4 v = *(const float4*)(s + (size_t)(k0 + kk) * Nd + n0 + nn);
        tl[kk][nn] = v.x; tl[kk][nn + 1] = v.y; tl[kk][nn + 2] = v.z; tl[kk][nn + 3] = v.w;
    }
    __syncthreads();
    #pragma unroll
    for (int g = 0; g < 4; ++g) {
        int flat = g * 1024 + tid * 4;
        int nn = flat >> 6, kk = flat & 63;
        uint2 o;
        o.x = (unsigned)f2bf(tl[kk][nn])     | ((unsigned)f2bf(tl[kk + 1][nn]) << 16);
        o.y = (unsigned)f2bf(tl[kk + 2][nn]) | ((unsigned)f2bf(tl[kk + 3][nn]) << 16);
        *(uint2*)(d + (size_t)(n0 + nn) * Kd + k0 + kk) = o;
    }
}

// ---------------- grouped bf16 MFMA GEMM: 128x128, BK=32, 2-buffer, 5 blocks/CU ----------------
// C = act(A . B^T + bias). A: rows of Kd bf16 (via tmap if GATHER, else slot rows).
// B: [E][Nd][Kd] bf16 (K-contiguous). C: [E][CAP][Nd] bf16.
// Round-11 discriminating probe (TLP-wall vs per-CU-structural-wall):
//   rounds 7-10 show per-block-iter serial cost ~const and hidden ONLY by multi-block
//   TLP (3 blk/CU best; 1 blk/CU catastrophic). This round maximizes TLP: 32 KiB LDS
//   -> 5 blocks/CU, 20 waves/CU. Regs 72 VGPR + 64 AGPR = 136 <= 2048/5 per SIMD.
// Pipeline (proven round 9): STAGE(t+1 -> other buf); ds_reads+MFMA(t); vmcnt(0); barrier.
// Loads get the full compute phase to land; residual stall hidden by 5-way TLP.
// LDS: linear [128 rows][32 k] per matrix (r7 proved 64-B-row swizzle is a no-op;
// ~2.1e7 conflict cycles absorbed). Grid: 3-D (bx, by, e), bx fastest (r8 locality).
#define SCHED0() __builtin_amdgcn_sched_barrier(0)
#define VMC0()   do { asm volatile("s_waitcnt vmcnt(0)" ::: "memory"); } while (0)

template<bool DOGELU, bool GATHER>
__global__ __launch_bounds__(256, 5) void k_gemm(const ushort* __restrict__ A,
                                                 const int* __restrict__ tmap,
                                                 const ushort* __restrict__ B,
                                                 const float* __restrict__ bias,
                                                 ushort* __restrict__ C,
                                                 int Kd, int Nd) {
    __shared__ __attribute__((aligned(128))) char lds[32768];   // 2 x (A 8K + B 8K)
    const int tid  = threadIdx.x;
    const int lane = tid & 63;
    const int wave = tid >> 6;
    const int wr = wave >> 1, wc = wave & 1;      // 2x2 wave grid, 64x64 out each
    const int e = blockIdx.z;
    const int bm0 = blockIdx.y * 128, bn0 = blockIdx.x * 128;

    const ushort* Be = B + (size_t)e * (size_t)Nd * Kd;
    // staging map: thread tid -> rows R, R+64 (R = tid>>2); k-chunk kc = (tid&3)*8 elems.
    // LDS byte offset = R*64 + (tid&3)*16 = tid*16 (linear)
    const int R  = tid >> 2;
    const int kc = (tid & 3) * 8;
    int ra0, ra1;
    if (GATHER) { ra0 = tmap[e * CAP + bm0 + R]; ra1 = tmap[e * CAP + bm0 + R + 64]; }
    else        { ra0 = e * CAP + bm0 + R;       ra1 = e * CAP + bm0 + R + 64; }
    const ushort* pa0 = A + (size_t)ra0 * Kd + kc;
    const ushort* pa1 = A + (size_t)ra1 * Kd + kc;
    const ushort* pb0 = Be + (size_t)(bn0 + R) * Kd + kc;
    const ushort* pb1 = Be + (size_t)(bn0 + R + 64) * Kd + kc;

    auto STAGE = [&](int buf, int kt) {
        char* d = lds + buf * 16384;
        gload16(pa0 + kt * BK, d + tid * 16);          // A rows 0-63
        gload16(pa1 + kt * BK, d + 4096 + tid * 16);   // A rows 64-127
        gload16(pb0 + kt * BK, d + 8192 + tid * 16);   // B rows 0-63
        gload16(pb1 + kt * BK, d + 12288 + tid * 16);  // B rows 64-127
    };

    // compute-side fragment addressing (linear: chunk = kq)
    const int fr = lane & 15, kq = lane >> 4;
    const int cb = kq * 16;                       // byte offset of 16B chunk within 64B row
    int offA[4], offB[4];
    #pragma unroll
    for (int mi = 0; mi < 4; ++mi) offA[mi] = (wr * 64 + mi * 16 + fr) * 64 + cb;
    #pragma unroll
    for (int ni = 0; ni < 4; ++ni) offB[ni] = 8192 + (wc * 64 + ni * 16 + fr) * 64 + cb;

    f32x4 acc[4][4] = {};
    const int nt = Kd / BK;

    STAGE(0, 0);
    VMC0();
    __builtin_amdgcn_s_barrier();
    for (int t = 0; t < nt; ++t) {
        if (t + 1 < nt) STAGE((t + 1) & 1, t + 1);
        SCHED0();
        const char* rb = lds + (t & 1) * 16384;
        bf16x8 af[4], bf[4];
        #pragma unroll
        for (int mi = 0; mi < 4; ++mi) af[mi] = *(const bf16x8*)(rb + offA[mi]);
        #pragma unroll
        for (int ni = 0; ni < 4; ++ni) bf[ni] = *(const bf16x8*)(rb + offB[ni]);
        #pragma unroll
        for (int mi = 0; mi < 4; ++mi)
            #pragma unroll
            for (int ni = 0; ni < 4; ++ni)
                acc[mi][ni] = __builtin_amdgcn_mfma_f32_16x16x32_bf16(af[mi], bf[ni],
                                                                      acc[mi][ni], 0, 0, 0);
        VMC0();                                    // tile t+1 landed (issued a full phase ago)
        __builtin_amdgcn_s_barrier();              // publish buf[(t+1)&1]; reads of t done
    }

    const float* be = bias + e * Nd;
    ushort* Ce = C + (size_t)e * CAP * Nd;
    const int rl = (lane >> 4) * 4, cl = lane & 15;
    #pragma unroll
    for (int mi = 0; mi < 4; ++mi) {
        #pragma unroll
        for (int ni = 0; ni < 4; ++ni) {
            #pragma unroll
            for (int r = 0; r < 4; ++r) {
                int gr = bm0 + wr * 64 + mi * 16 + rl + r;
                int gc = bn0 + wc * 64 + ni * 16 + cl;
                float v = acc[mi][ni][r] + be[gc];
                if (DOGELU) v = 0.5f * v * (1.f + erff(v * 0.70710678118654752f));
                Ce[(size_t)gr * Nd + gc] = f2bf(v);
            }
        }
    }
}

// ---------------- deterministic combine: out[t] = sum_k p_k * Y[dest_k] ----------------
__global__ void k_combine(const ushort* __restrict__ Y, const int* __restrict__ dest,
                          const float* __restrict__ probs, float* __restrict__ out) {
    int t = blockIdx.x;
    int h0 = threadIdx.x * 8;
    int d0 = dest[t * 2], d1 = dest[t * 2 + 1];
    float p0 = d0 >= 0 ? probs[t * 2] : 0.f;
    float p1 = d1 >= 0 ? probs[t * 2 + 1] : 0.f;
    int r0 = d0 >= 0 ? d0 : 0, r1 = d1 >= 0 ? d1 : 0;
    uint4 a = *(const uint4*)(Y + (size_t)r0 * HDIM + h0);
    uint4 b = *(const uint4*)(Y + (size_t)r1 * HDIM + h0);
    float4 o0, o1;
    o0.x = p0 * bf2f(a.x & 0xffff) + p1 * bf2f(b.x & 0xffff);
    o0.y = p0 * bf2f(a.x >> 16)    + p1 * bf2f(b.x >> 16);
    o0.z = p0 * bf2f(a.y & 0xffff) + p1 * bf2f(b.y & 0xffff);
    o0.w = p0 * bf2f(a.y >> 16)    + p1 * bf2f(b.y >> 16);
    o1.x = p0 * bf2f(a.z & 0xffff) + p1 * bf2f(b.z & 0xffff);
    o1.y = p0 * bf2f(a.z >> 16)    + p1 * bf2f(b.z >> 16);
    o1.z = p0 * bf2f(a.w & 0xffff) + p1 * bf2f(b.w & 0xffff);
    o1.w = p0 * bf2f(a.w >> 16)    + p1 * bf2f(b.w >> 16);
    float* op = out + (size_t)t * HDIM + h0;
    *(float4*)op = o0;
    *(float4*)(op + 4) = o1;
}

extern "C" void kernel_launch(void* const* d_in, const int* in_sizes, int n_in,
                              void* d_out, int out_size, void* d_ws, size_t ws_size,
                              hipStream_t stream) {
    const float* tokens = (const float*)d_in[0];
    const float* Wr     = (const float*)d_in[1];
    const float* br     = (const float*)d_in[2];
    const float* W1     = (const float*)d_in[3];
    const float* b1     = (const float*)d_in[4];
    const float* W2     = (const float*)d_in[5];
    const float* b2     = (const float*)d_in[6];
    float* out = (float*)d_out;
    char* ws = (char*)d_ws;

    int*    eids    = (int*)(ws);
    float*  probs   = (float*)(ws + 65536);
    int*    tok_map = (int*)(ws + 131072);
    int*    dest    = (int*)(ws + 172032);
    size_t off = 1u << 20;
    ushort* TbY = (ushort*)(ws + off);             // tokens bf16 (33.5 MB) then Y bf16 (41.9 MB)
    off += 41943040;
    ushort* Hm  = (ushort*)(ws + off);             // gelu hidden bf16, 83.9 MB
    off += 83886080;
    ushort* WT  = (ushort*)(ws + off);             // W1T then W2T bf16, 134.2 MB
    (void)in_sizes; (void)n_in; (void)out_size; (void)ws_size;

    k_convert<<<dim3(NTOK * HDIM / 2048), 256, 0, stream>>>(tokens, TbY);
    k_router<<<dim3(NTOK / 4), 256, 0, stream>>>(tokens, Wr, br, eids, probs);
    k_assign<<<dim3(1), 64, 0, stream>>>(eids, tok_map, dest);
    k_transpose<<<dim3(HDIM / 64, FF / 64, NEXP), 256, 0, stream>>>(W1, WT, HDIM, FF);
    k_gemm<true, true><<<dim3(FF / 128, CAP / 128, NEXP), 256, 0, stream>>>(
        TbY, tok_map, WT, b1, Hm, HDIM, FF);
    k_transpose<<<dim3(FF / 64, HDIM / 64, NEXP), 256, 0, stream>>>(W2, WT, FF, HDIM);
    k_gemm<false, false><<<dim3(HDIM / 128, CAP / 128, NEXP), 256, 0, stream>>>(
        Hm, nullptr, WT, b2, TbY, FF, HDIM);
    k_combine<<<dim3(NTOK), 256, 0, stream>>>(TbY, dest, probs, out);
}

// Round 12
// 776.018 us; speedup vs baseline: 1.0506x; 1.0506x over previous
//
#include <hip/hip_runtime.h>
#include <hip/hip_bf16.h>
#include <math.h>

// Problem constants (reference: N=8192, H=2048, E=8, K=2, CF=1.25)
#define NTOK 8192
#define HDIM 2048
#define NEXP 8
#define TOPK 2
#define CAP  1280            // ceil(1.25 * 8192 / 8)
#define FF   4096            // 2*H
#define BK   32              // GEMM K-step

typedef float  f32x4  __attribute__((ext_vector_type(4)));
typedef __bf16 bf16x8 __attribute__((ext_vector_type(8)));

typedef __attribute__((address_space(1))) const unsigned int gas_u32;
typedef __attribute__((address_space(3))) unsigned int las_u32;

__device__ __forceinline__ void gload16(const void* g, void* l) {
    // async global -> LDS, 16 B per lane; LDS dest = wave-uniform base + lane*16
    __builtin_amdgcn_global_load_lds((gas_u32*)g, (las_u32*)l, 16, 0, 0);
}

__device__ __forceinline__ ushort f2bf(float f) {
    union { float f; unsigned u; } c; c.f = f;
    unsigned u = c.u;
    unsigned r = (u + 0x7FFFu + ((u >> 16) & 1u)) >> 16;   // RNE
    return (ushort)r;
}
__device__ __forceinline__ float bf2f(ushort h) {
    union { unsigned u; float f; } c; c.u = ((unsigned)h) << 16;
    return c.f;
}

// ---------------- fused router + tokens->bf16 convert ----------------
// 4 waves/block, one token row per wave. Vectorized float4 reads; f64 accum
// (deterministic fixed order); writes bf16 row + top-2 expert ids/probs.
__global__ __launch_bounds__(256) void k_router(const float* __restrict__ tokens,
                                                const float* __restrict__ Wr,
                                                const float* __restrict__ br,
                                                int* __restrict__ eids,
                                                float* __restrict__ probs,
                                                ushort* __restrict__ Tb) {
    int wave = threadIdx.x >> 6, lane = threadIdx.x & 63;
    int t = blockIdx.x * 4 + wave;
    const float* tp = tokens + (size_t)t * HDIM;
    ushort* tb = Tb + (size_t)t * HDIM;
    double acc[NEXP];
    #pragma unroll
    for (int e = 0; e < NEXP; ++e) acc[e] = 0.0;
    #pragma unroll
    for (int c = 0; c < HDIM / 256; ++c) {
        float4 v = *(const float4*)(tp + c * 256 + lane * 4);
        uint2 o;
        o.x = (unsigned)f2bf(v.x) | ((unsigned)f2bf(v.y) << 16);
        o.y = (unsigned)f2bf(v.z) | ((unsigned)f2bf(v.w) << 16);
        *(uint2*)(tb + c * 256 + lane * 4) = o;
        #pragma unroll
        for (int e = 0; e < NEXP; ++e) {
            float4 w = *(const float4*)(Wr + e * HDIM + c * 256 + lane * 4);
            acc[e] += (double)v.x * (double)w.x + (double)v.y * (double)w.y
                    + (double)v.z * (double)w.z + (double)v.w * (double)w.w;
        }
    }
    #pragma unroll
    for (int e = 0; e < NEXP; ++e) {
        #pragma unroll
        for (int off = 32; off; off >>= 1) acc[e] += __shfl_xor(acc[e], off, 64);
    }
    if (lane == 0) {
        float lg[NEXP];
        #pragma unroll
        for (int e = 0; e < NEXP; ++e) lg[e] = (float)acc[e] + br[e];
        int e0 = 0; float s0 = lg[0];
        #pragma unroll
        for (int e = 1; e < NEXP; ++e) if (lg[e] > s0) { s0 = lg[e]; e0 = e; }
        int e1 = -1; float s1 = -1e30f;
        #pragma unroll
        for (int e = 0; e < NEXP; ++e) if (e != e0 && lg[e] > s1) { s1 = lg[e]; e1 = e; }
        float ex = expf(s1 - s0);
        float den = 1.f + ex;
        eids[t * 2] = e0; eids[t * 2 + 1] = e1;
        probs[t * 2] = 1.f / den; probs[t * 2 + 1] = ex / den;
    }
}

// ---------------- deterministic rank/capacity assignment (1 block, 1 wave) ----------------
__global__ void k_assign(const int* __restrict__ eids, int* __restrict__ tok_map,
                         int* __restrict__ dest) {
    __shared__ int cnt[64][NEXP];
    int l = threadIdx.x;
    for (int i = l; i < NEXP * CAP; i += 64) tok_map[i] = 0;
    int c[NEXP];
    #pragma unroll
    for (int e = 0; e < NEXP; ++e) c[e] = 0;
    const int base = l * 256;
    for (int i = 0; i < 256; ++i) {
        int ee = eids[base + i];
        #pragma unroll
        for (int e = 0; e < NEXP; ++e) c[e] += (ee == e);
    }
    #pragma unroll
    for (int e = 0; e < NEXP; ++e) cnt[l][e] = c[e];
    __syncthreads();
    if (l < NEXP) {
        int run = 0;
        for (int b = 0; b < 64; ++b) { int v = cnt[b][l]; cnt[b][l] = run; run += v; }
    }
    __syncthreads();
    int off[NEXP];
    #pragma unroll
    for (int e = 0; e < NEXP; ++e) off[e] = cnt[l][e];
    for (int i = 0; i < 256; ++i) {
        int d = base + i;
        int ee = eids[d];
        int r = -1;
        #pragma unroll
        for (int e = 0; e < NEXP; ++e) { bool m = (ee == e); if (m) r = off[e]; off[e] += m; }
        if (r < CAP) { tok_map[ee * CAP + r] = d >> 1; dest[d] = ee * CAP + r; }
        else dest[d] = -1;
    }
}

// ---------------- W [E][Kd][Nd] f32 -> WT [E][Nd][Kd] bf16, 64x64 tiles ----------------
__global__ __launch_bounds__(256) void k_transpose(const float* __restrict__ src,
                                                   ushort* __restrict__ dst,
                                                   int Kd, int Nd) {
    __shared__ float tl[64][65];
    int e = blockIdx.z;
    int k0 = blockIdx.x * 64, n0 = blockIdx.y * 64;
    const float* s = src + (size_t)e * Kd * Nd;
    ushort* d = dst + (size_t)e * Kd * Nd;
    int tid = threadIdx.x;
    #pragma unroll
    for (int i = 0; i < 4; ++i) {
        int flat = (i * 256 + tid) * 4;
        int kk = flat >> 6, nn = flat & 63;
        float4 v = *(const float4*)(s + (size_t)(k0 + kk) * Nd + n0 + nn);
        tl[kk][nn] = v.x; tl[kk][nn + 1] = v.y; tl[kk][nn + 2] = v.z; tl[kk][nn + 3] = v.w;
    }
    __syncthreads();
    #pragma unroll
    for (int g = 0; g < 4; ++g) {
        int flat = g * 1024 + tid * 4;
        int nn = flat >> 6, kk = flat & 63;
        uint2 o;
        o.x = (unsigned)f2bf(tl[kk][nn])     | ((unsigned)f2bf(tl[kk + 1][nn]) << 16);
        o.y = (unsigned)f2bf(tl[kk + 2][nn]) | ((unsigned)f2bf(tl[kk + 3][nn]) << 16);
        *(uint2*)(d + (size_t)(n0 + nn) * Kd + k0 + kk) = o;
    }
}

// ---------------- grouped bf16 MFMA GEMM: 128x128, BK=32, 4-buffer depth-3 ----------------
// C = act(A . B^T + bias). A: rows of Kd bf16 (via tmap if GATHER, else slot rows).
// B: [E][Nd][Kd] bf16 (K-contiguous). C: [E][CAP][Nd] bf16.
// Round-12 change (r11 falsified raw-TLP; depth x blocks covering load latency is the
// correlate): 4 LDS buffers (64 KiB -> 2 blk/CU), prefetch DEPTH 3, vmcnt(8) per iter
// (outstanding = tiles t+1,t+2 = 8 loads; the 4 oldest = tile t confirmed). Loads get
// ~3 compute phases (~1650 cyc) to land -- above worst HBM-miss + queueing for the
// gathered A rows. Tail dup-stages min(t+3,nt-1); WAR on buf[(t+3)&3] cleared by
// barrier t (reads of tile t-1 done before it). Grid: 3-D, bx fastest (r8 locality).
// LDS linear (r7: 64-B-row chunk swizzle is a no-op; ~2.1e7 conflict cyc absorbed).
#define SCHED0() __builtin_amdgcn_sched_barrier(0)
#define VMC8()   do { asm volatile("s_waitcnt vmcnt(8)" ::: "memory"); } while (0)

template<bool DOGELU, bool GATHER>
__global__ __launch_bounds__(256) void k_gemm(const ushort* __restrict__ A,
                                              const int* __restrict__ tmap,
                                              const ushort* __restrict__ B,
                                              const float* __restrict__ bias,
                                              ushort* __restrict__ C,
                                              int Kd, int Nd) {
    __shared__ __attribute__((aligned(128))) char lds[65536];   // 4 x (A 8K + B 8K)
    const int tid  = threadIdx.x;
    const int lane = tid & 63;
    const int wave = tid >> 6;
    const int wr = wave >> 1, wc = wave & 1;      // 2x2 wave grid, 64x64 out each
    const int e = blockIdx.z;
    const int bm0 = blockIdx.y * 128, bn0 = blockIdx.x * 128;

    const ushort* Be = B + (size_t)e * (size_t)Nd * Kd;
    // staging map: thread tid -> rows R, R+64 (R = tid>>2); k-chunk kc = (tid&3)*8 elems.
    // LDS byte offset = R*64 + (tid&3)*16 = tid*16 (linear)
    const int R  = tid >> 2;
    const int kc = (tid & 3) * 8;
    int ra0, ra1;
    if (GATHER) { ra0 = tmap[e * CAP + bm0 + R]; ra1 = tmap[e * CAP + bm0 + R + 64]; }
    else        { ra0 = e * CAP + bm0 + R;       ra1 = e * CAP + bm0 + R + 64; }
    const ushort* pa0 = A + (size_t)ra0 * Kd + kc;
    const ushort* pa1 = A + (size_t)ra1 * Kd + kc;
    const ushort* pb0 = Be + (size_t)(bn0 + R) * Kd + kc;
    const ushort* pb1 = Be + (size_t)(bn0 + R + 64) * Kd + kc;

    auto STAGE = [&](int buf, int kt) {
        char* d = lds + buf * 16384;
        gload16(pa0 + kt * BK, d + tid * 16);          // A rows 0-63
        gload16(pa1 + kt * BK, d + 4096 + tid * 16);   // A rows 64-127
        gload16(pb0 + kt * BK, d + 8192 + tid * 16);   // B rows 0-63
        gload16(pb1 + kt * BK, d + 12288 + tid * 16);  // B rows 64-127
    };

    // compute-side fragment addressing (linear: chunk = kq)
    const int fr = lane & 15, kq = lane >> 4;
    const int cb = kq * 16;                       // byte offset of 16B chunk within 64B row
    int offA[4], offB[4];
    #pragma unroll
    for (int mi = 0; mi < 4; ++mi) offA[mi] = (wr * 64 + mi * 16 + fr) * 64 + cb;
    #pragma unroll
    for (int ni = 0; ni < 4; ++ni) offB[ni] = 8192 + (wc * 64 + ni * 16 + fr) * 64 + cb;

    f32x4 acc[4][4] = {};
    const int nt = Kd / BK;

    STAGE(0, 0); STAGE(1, 1); STAGE(2, 2);         // vm queue: 12
    for (int t = 0; t < nt; ++t) {
        VMC8();                                    // oldest 4 = tile t landed (queue -> 8)
        __builtin_amdgcn_s_barrier();              // publish tile t; reads of t-1 done
        SCHED0();
        STAGE((t + 3) & 3, min(t + 3, nt - 1));    // refill queue to 12 (dup-stage at tail)
        const char* rb = lds + (t & 3) * 16384;
        bf16x8 af[4], bf[4];
        #pragma unroll
        for (int mi = 0; mi < 4; ++mi) af[mi] = *(const bf16x8*)(rb + offA[mi]);
        #pragma unroll
        for (int ni = 0; ni < 4; ++ni) bf[ni] = *(const bf16x8*)(rb + offB[ni]);
        #pragma unroll
        for (int mi = 0; mi < 4; ++mi)
            #pragma unroll
            for (int ni = 0; ni < 4; ++ni)
                acc[mi][ni] = __builtin_amdgcn_mfma_f32_16x16x32_bf16(af[mi], bf[ni],
                                                                      acc[mi][ni], 0, 0, 0);
    }

    const float* be = bias + e * Nd;
    ushort* Ce = C + (size_t)e * CAP * Nd;
    const int rl = (lane >> 4) * 4, cl = lane & 15;
    #pragma unroll
    for (int mi = 0; mi < 4; ++mi) {
        #pragma unroll
        for (int ni = 0; ni < 4; ++ni) {
            #pragma unroll
            for (int r = 0; r < 4; ++r) {
                int gr = bm0 + wr * 64 + mi * 16 + rl + r;
                int gc = bn0 + wc * 64 + ni * 16 + cl;
                float v = acc[mi][ni][r] + be[gc];
                if (DOGELU) v = 0.5f * v * (1.f + erff(v * 0.70710678118654752f));
                Ce[(size_t)gr * Nd + gc] = f2bf(v);
            }
        }
    }
}

// ---------------- deterministic combine: out[t] = sum_k p_k * Y[dest_k] ----------------
__global__ void k_combine(const ushort* __restrict__ Y, const int* __restrict__ dest,
                          const float* __restrict__ probs, float* __restrict__ out) {
    int t = blockIdx.x;
    int h0 = threadIdx.x * 8;
    int d0 = dest[t * 2], d1 = dest[t * 2 + 1];
    float p0 = d0 >= 0 ? probs[t * 2] : 0.f;
    float p1 = d1 >= 0 ? probs[t * 2 + 1] : 0.f;
    int r0 = d0 >= 0 ? d0 : 0, r1 = d1 >= 0 ? d1 : 0;
    uint4 a = *(const uint4*)(Y + (size_t)r0 * HDIM + h0);
    uint4 b = *(const uint4*)(Y + (size_t)r1 * HDIM + h0);
    float4 o0, o1;
    o0.x = p0 * bf2f(a.x & 0xffff) + p1 * bf2f(b.x & 0xffff);
    o0.y = p0 * bf2f(a.x >> 16)    + p1 * bf2f(b.x >> 16);
    o0.z = p0 * bf2f(a.y & 0xffff) + p1 * bf2f(b.y & 0xffff);
    o0.w = p0 * bf2f(a.y >> 16)    + p1 * bf2f(b.y >> 16);
    o1.x = p0 * bf2f(a.z & 0xffff) + p1 * bf2f(b.z & 0xffff);
    o1.y = p0 * bf2f(a.z >> 16)    + p1 * bf2f(b.z >> 16);
    o1.z = p0 * bf2f(a.w & 0xffff) + p1 * bf2f(b.w & 0xffff);
    o1.w = p0 * bf2f(a.w >> 16)    + p1 * bf2f(b.w >> 16);
    float* op = out + (size_t)t * HDIM + h0;
    *(float4*)op = o0;
    *(float4*)(op + 4) = o1;
}

extern "C" void kernel_launch(void* const* d_in, const int* in_sizes, int n_in,
                              void* d_out, int out_size, void* d_ws, size_t ws_size,
                              hipStream_t stream) {
    const float* tokens = (const float*)d_in[0];
    const float* Wr     = (const float*)d_in[1];
    const float* br     = (const float*)d_in[2];
    const float* W1     = (const float*)d_in[3];
    const float* b1     = (const float*)d_in[4];
    const float* W2     = (const float*)d_in[5];
    const float* b2     = (const float*)d_in[6];
    float* out = (float*)d_out;
    char* ws = (char*)d_ws;

    int*    eids    = (int*)(ws);
    float*  probs   = (float*)(ws + 65536);
    int*    tok_map = (int*)(ws + 131072);
    int*    dest    = (int*)(ws + 172032);
    size_t off = 1u << 20;
    ushort* TbY = (ushort*)(ws + off);             // tokens bf16 (33.5 MB) then Y bf16 (41.9 MB)
    off += 41943040;
    ushort* Hm  = (ushort*)(ws + off);             // gelu hidden bf16, 83.9 MB
    off += 83886080;
    ushort* WT  = (ushort*)(ws + off);             // W1T then W2T bf16, 134.2 MB
    (void)in_sizes; (void)n_in; (void)out_size; (void)ws_size;

    k_router<<<dim3(NTOK / 4), 256, 0, stream>>>(tokens, Wr, br, eids, probs, TbY);
    k_assign<<<dim3(1), 64, 0, stream>>>(eids, tok_map, dest);
    k_transpose<<<dim3(HDIM / 64, FF / 64, NEXP), 256, 0, stream>>>(W1, WT, HDIM, FF);
    k_gemm<true, true><<<dim3(FF / 128, CAP / 128, NEXP), 256, 0, stream>>>(
        TbY, tok_map, WT, b1, Hm, HDIM, FF);
    k_transpose<<<dim3(FF / 64, HDIM / 64, NEXP), 256, 0, stream>>>(W2, WT, FF, HDIM);
    k_gemm<false, false><<<dim3(HDIM / 128, CAP / 128, NEXP), 256, 0, stream>>>(
        Hm, nullptr, WT, b2, TbY, FF, HDIM);
    k_combine<<<dim3(NTOK), 256, 0, stream>>>(TbY, dest, probs, out);
}